// Round 10
// baseline (42.353 us; speedup 1.0000x reference)
//
#include <hip/hip_runtime.h>

#define H 512
#define W 512
#define NW 4               // waves per block
#define SLOTS 4            // wave-private ring slots (1 target row each)

// Full-wave (64-lane) sum using DPP only — pure VALU. Result in lane 63.
__device__ __forceinline__ float wave_sum_dpp(float x) {
#define DPP_STEP(ctrl)                                                          \
    x += __int_as_float(__builtin_amdgcn_update_dpp(                            \
        0, __float_as_int(x), (ctrl), 0xF, 0xF, true))
    DPP_STEP(0x111);   // row_shr:1
    DPP_STEP(0x112);   // row_shr:2
    DPP_STEP(0x114);   // row_shr:4
    DPP_STEP(0x118);   // row_shr:8
    DPP_STEP(0x142);   // row_bcast:15
    DPP_STEP(0x143);   // row_bcast:31
#undef DPP_STEP
    return x;
}

__device__ __forceinline__ float4 ld4(const float* p) {
    return *reinterpret_cast<const float4*>(p);
}
__device__ __forceinline__ float2 ld2(const float* p) {
    return *reinterpret_cast<const float2*>(p);
}

// Async global->LDS DMA, 16 B/lane, linear dest (base + lane*16). Compiler
// models this intrinsic's vmcnt effect — unlike R9's raw asm loads.
__device__ __forceinline__ void gl_lds16(const float* g, float* l) {
    __builtin_amdgcn_global_load_lds(
        (const __attribute__((address_space(1))) void*)g,
        (__attribute__((address_space(3))) void*)l,
        16, 0, 0);
}

// Counted vmcnt wait ("memory" clobber orders all loads/DMA issues across it;
// sched_barrier(0) per rule #18).
#define WAITV(n) do { asm volatile("s_waitcnt vmcnt(" #n ")" ::: "memory");     \
                      __builtin_amdgcn_sched_barrier(0); } while (0)

// Kernel 1: per-wave DMA ring pipeline, ZERO barriers in the hot path.
// One wave owns 4 full image rows (64 lanes x 8 px = 512 = W) in registers and
// streams its 8 target rows (y0-2..y0+5) through a private 4-slot LDS ring:
// issue row t+3, wait vmcnt(6) (exactly row t landed, FIFO), consume from LDS.
__global__ __launch_bounds__(256, 4)
void dice_partial(const float* __restrict__ in, const float* __restrict__ tg,
                  float* __restrict__ ws, int nblocks) {
    __shared__ __align__(16) float ring[NW][SLOTS][W];   // 32 KB, wave-private
    __shared__ float warr[NW][32];                       // [wave][quantity]

    const int tid  = threadIdx.x;
    const int wave = tid >> 6, lane = tid & 63;

    const int bid = blockIdx.x;
    const int wrk = (bid & 7) * (nblocks >> 3) + (bid >> 3);   // XCD chunking

    const int q  = wrk * 4 + wave;     // global row-quad id
    const int b  = q >> 7;             // image (128 quads per image)
    const int y0 = (q & 127) << 2;     // first of 4 owned rows (<= 508)
    const float* __restrict__ inb = in + (size_t)b * (H * W);
    const float* __restrict__ tgb = tg + (size_t)b * (H * W);

    const int c0 = lane * 8;           // my 8 columns

    // ---- 1) plain input loads (the only vmem ops so far) ----
    float4 ia[4], ic[4];
#pragma unroll
    for (int yi = 0; yi < 4; ++yi) {
        const float* rp = inb + (size_t)(y0 + yi) * W;
        ia[yi] = ld4(rp + c0);
        ic[yi] = ld4(rp + c0 + 4);
    }
    // ---- 2) one-time drain: from here on vmcnt counts ONLY ring DMAs ----
    WAITV(0);

    // ---- 3) DMA target rows 0..2 into slots 0..2 (2 events per row) ----
#define TISSUE(t, slot) {                                                       \
        const float* rp = tgb + (size_t)((y0 - 2 + (t)) & (H - 1)) * W;         \
        gl_lds16(rp + lane * 4,       &ring[wave][slot][0]);                    \
        gl_lds16(rp + 256 + lane * 4, &ring[wave][slot][256]); }
    TISSUE(0, 0)
    TISSUE(1, 1)
    TISSUE(2, 2)

    // ---- 4) unpack inputs + isum (overlaps DMA flight) ----
    float iv[4][8];
    float isum = 0.f;
#pragma unroll
    for (int yi = 0; yi < 4; ++yi) {
        iv[yi][0] = ia[yi].x; iv[yi][1] = ia[yi].y;
        iv[yi][2] = ia[yi].z; iv[yi][3] = ia[yi].w;
        iv[yi][4] = ic[yi].x; iv[yi][5] = ic[yi].y;
        iv[yi][6] = ic[yi].z; iv[yi][7] = ic[yi].w;
#pragma unroll
        for (int j = 0; j < 8; ++j) isum += iv[yi][j];
    }
    isum = wave_sum_dpp(isum);
    if (lane == 63) warr[wave][25] = isum;

    float acc[25];
#pragma unroll
    for (int k = 0; k < 25; ++k) acc[k] = 0.f;
    float tsum = 0.f;

    // ---- 5) steady pipeline: issue t+3, wait row t (FIFO-exact), consume ----
#define CONSUME(t) {                                                            \
        const float* rowp = &ring[wave][(t) & 3][0];                            \
        float tw[12];                                                           \
        const float4 a  = ld4(rowp + c0);                                       \
        const float4 cc = ld4(rowp + c0 + 4);                                   \
        const float2 lf = ld2(rowp + ((c0 - 2) & (W - 1)));                     \
        const float2 rg = ld2(rowp + ((c0 + 8) & (W - 1)));                     \
        tw[0]  = lf.x; tw[1]  = lf.y;                                           \
        tw[2]  = a.x;  tw[3]  = a.y;  tw[4] = a.z;  tw[5] = a.w;                \
        tw[6]  = cc.x; tw[7]  = cc.y; tw[8] = cc.z; tw[9] = cc.w;               \
        tw[10] = rg.x; tw[11] = rg.y;                                           \
        if ((t) >= 2 && (t) <= 5) {                                             \
            _Pragma("unroll")                                                   \
            for (int j = 0; j < 8; ++j) tsum += tw[j + 2];                      \
        }                                                                       \
        _Pragma("unroll")                                                       \
        for (int yi = 0; yi < 4; ++yi) {                                        \
            const int sy = yi + 2 - (t);                                        \
            if (sy < -2 || sy > 2) continue;                                    \
            _Pragma("unroll")                                                   \
            for (int sx = -2; sx <= 2; ++sx) {                                  \
                _Pragma("unroll")                                               \
                for (int j = 0; j < 8; ++j)                                     \
                    acc[(sy + 2) * 5 + (sx + 2)] += iv[yi][j] * tw[j + 2 - sx]; \
            }                                                                   \
        }                                                                       \
    }

    TISSUE(3, 3)  WAITV(6);  CONSUME(0)
    TISSUE(4, 0)  WAITV(6);  CONSUME(1)
    TISSUE(5, 1)  WAITV(6);  CONSUME(2)
    TISSUE(6, 2)  WAITV(6);  CONSUME(3)
    TISSUE(7, 3)  WAITV(6);  CONSUME(4)
    /* tail */    WAITV(4);  CONSUME(5)
                  WAITV(2);  CONSUME(6)
                  WAITV(0);  CONSUME(7)
#undef CONSUME
#undef TISSUE

    // ---- 6) per-wave DPP reduction of remaining quantities ----
#pragma unroll
    for (int k = 0; k < 25; ++k) {
        const float v = wave_sum_dpp(acc[k]);
        if (lane == 63) warr[wave][k] = v;
    }
    {
        const float u = wave_sum_dpp(tsum);
        if (lane == 63) warr[wave][26] = u;
    }

    __syncthreads();
    if (tid < 27) {
        const float s = warr[0][tid] + warr[1][tid] + warr[2][tid] + warr[3][tid];
        ws[tid * nblocks + bid] = s;   // [k][block] layout for coalesced pass 2
    }
}

// Kernel 2: 27 blocks, block k tree-reduces the per-block partials for quantity k.
__global__ __launch_bounds__(256)
void dice_reduce(const float* __restrict__ ws, float* __restrict__ tot, int nblocks) {
    __shared__ float red[4];
    const int k = blockIdx.x;
    const int tid = threadIdx.x;
    const float* p = ws + (size_t)k * nblocks;

    float s = 0.f;
    for (int i = tid; i < nblocks; i += 256) s += p[i];
    s = wave_sum_dpp(s);
    if ((tid & 63) == 63) red[tid >> 6] = s;
    __syncthreads();
    if (tid == 0) tot[k] = red[0] + red[1] + red[2] + red[3];
}

// Kernel 3: one wave — 25-way max + final loss scalar.
__global__ void dice_out(const float* __restrict__ tot, float* __restrict__ out) {
    const int tid = threadIdx.x;   // blockDim = 64
    float v = (tid < 25) ? tot[tid] : -1e30f;
#pragma unroll
    for (int off = 32; off; off >>= 1) v = fmaxf(v, __shfl_down(v, off, 64));
    if (tid == 0) {
        const float denom = tot[25] + tot[26] + 1.0f;   // i_sum + t_sum + SMOOTH
        out[0] = 1.0f - (2.0f * v + 1.0f) / denom;      // min loss == max intersection
    }
}

extern "C" void kernel_launch(void* const* d_in, const int* in_sizes, int n_in,
                              void* d_out, int out_size, void* d_ws, size_t ws_size,
                              hipStream_t stream) {
    const float* inputs  = (const float*)d_in[0];
    const float* targets = (const float*)d_in[1];
    float* out = (float*)d_out;
    float* ws  = (float*)d_ws;

    const int B = in_sizes[0] / (H * W);    // 64
    const int nblocks = B * (H / 4) / 4;    // 2048 blocks x 4 waves x 4 rows

    float* tot = ws + (size_t)27 * nblocks; // 27 scalar totals after the partial table

    dice_partial<<<nblocks, 256, 0, stream>>>(inputs, targets, ws, nblocks);
    dice_reduce<<<27, 256, 0, stream>>>(ws, tot, nblocks);
    dice_out<<<1, 64, 0, stream>>>(tot, out);
}